// Round 2
// baseline (87.253 us; speedup 1.0000x reference)
//
#include <hip/hip_runtime.h>

// Problem constants (from setup_inputs): H=1536, W=2048, k=3, stride=4.
// k=3 is structural (window fully unrolled); stride read from d_in[2].
constexpr int H  = 1536;
constexpr int W  = 2048;
constexpr int PX = 8;                 // pixels per thread
// block = 256 threads = one full image row (256*8 = 2048); grid = H rows.

typedef float f32x4 __attribute__((ext_vector_type(4)));

__global__ __launch_bounds__(256)
void counting_post_kernel(const float* __restrict__ in,
                          const int* __restrict__ stride_p,
                          float* __restrict__ out) {
    const int r  = blockIdx.x;
    const int c0 = threadIdx.x * PX;
    const float s = (float)(*stride_p);

    // 3 rows x (PX+2) cols, relu'd, zero-padded at image borders.
    float v[3][PX + 2];
#pragma unroll
    for (int dr = 0; dr < 3; ++dr) {
        const int rr = r + dr - 1;
        if (rr < 0 || rr >= H) {
#pragma unroll
            for (int j = 0; j < PX + 2; ++j) v[dr][j] = 0.f;
        } else {
            const float* row = in + (size_t)rr * W + c0;
            const f32x4 a = *reinterpret_cast<const f32x4*>(row);
            const f32x4 b = *reinterpret_cast<const f32x4*>(row + 4);
            v[dr][1] = fmaxf(a.x, 0.f); v[dr][2] = fmaxf(a.y, 0.f);
            v[dr][3] = fmaxf(a.z, 0.f); v[dr][4] = fmaxf(a.w, 0.f);
            v[dr][5] = fmaxf(b.x, 0.f); v[dr][6] = fmaxf(b.y, 0.f);
            v[dr][7] = fmaxf(b.z, 0.f); v[dr][8] = fmaxf(b.w, 0.f);
            v[dr][0]      = (c0 > 0)      ? fmaxf(row[-1], 0.f) : 0.f;
            v[dr][PX + 1] = (c0 + PX < W) ? fmaxf(row[PX], 0.f) : 0.f;
        }
    }

    // Column sums and top/bottom-row differences (shared across the 8 pixels).
    float cs[PX + 2], dv[PX + 2];
#pragma unroll
    for (int j = 0; j < PX + 2; ++j) {
        cs[j] = v[0][j] + v[1][j] + v[2][j];
        dv[j] = v[2][j] - v[0][j];
    }

    float f_o[PX], cw_o[PX], ch_o[PX];
    const float rf = (float)r;
#pragma unroll
    for (int p = 0; p < PX; ++p) {
        const float sum = cs[p] + cs[p + 1] + cs[p + 2];
        // wh = (r-1)*rs0 + r*rs1 + (r+1)*rs2 = r*sum + (rs2 - rs0)
        const float dh  = dv[p] + dv[p + 1] + dv[p + 2];
        // ww = (c-1)*cs0 + c*cs1 + (c+1)*cs2 = c*sum + (cs2 - cs0)
        const float dw  = cs[p + 2] - cs[p];

        // argmax-first-occurrence == center: strictly > earlier taps, >= later.
        const float w11 = v[1][p + 1];
        const bool mask = (w11 >  v[0][p]) && (w11 >  v[0][p+1]) && (w11 >  v[0][p+2])
                       && (w11 >  v[1][p])
                       && (w11 >= v[1][p+2])
                       && (w11 >= v[2][p]) && (w11 >= v[2][p+1]) && (w11 >= v[2][p+2]);
        f_o[p] = (sum > 0.5f && mask) ? 1.f : 0.f;

        const float inv = 1.f / fmaxf(sum, 1e-12f);
        const float cf  = (float)(c0 + p);
        const float wh  = fmaf(rf, sum, dh);
        const float ww  = fmaf(cf, sum, dw);
        cw_o[p] = fmaf(s, ww * inv, 0.5f);
        ch_o[p] = fmaf(s, wh * inv, 0.5f);
    }

    // Write-once outputs: nontemporal to keep input rows resident in L2.
    const size_t base  = (size_t)r * W + c0;
    const size_t plane = (size_t)H * W;
    f32x4* o0 = reinterpret_cast<f32x4*>(out + base);
    f32x4* o1 = reinterpret_cast<f32x4*>(out + plane + base);
    f32x4* o2 = reinterpret_cast<f32x4*>(out + 2 * plane + base);
    __builtin_nontemporal_store((f32x4){f_o[0],  f_o[1],  f_o[2],  f_o[3]},  o0);
    __builtin_nontemporal_store((f32x4){f_o[4],  f_o[5],  f_o[6],  f_o[7]},  o0 + 1);
    __builtin_nontemporal_store((f32x4){cw_o[0], cw_o[1], cw_o[2], cw_o[3]}, o1);
    __builtin_nontemporal_store((f32x4){cw_o[4], cw_o[5], cw_o[6], cw_o[7]}, o1 + 1);
    __builtin_nontemporal_store((f32x4){ch_o[0], ch_o[1], ch_o[2], ch_o[3]}, o2);
    __builtin_nontemporal_store((f32x4){ch_o[4], ch_o[5], ch_o[6], ch_o[7]}, o2 + 1);
}

extern "C" void kernel_launch(void* const* d_in, const int* in_sizes, int n_in,
                              void* d_out, int out_size, void* d_ws, size_t ws_size,
                              hipStream_t stream) {
    const float* in     = (const float*)d_in[0];
    const int*   stride = (const int*)d_in[2];   // d_in[1] = loc_kernel_size (=3, structural)
    float*       out    = (float*)d_out;

    counting_post_kernel<<<H, 256, 0, stream>>>(in, stride, out);
}

// Round 3
// 85.284 us; speedup vs baseline: 1.0231x; 1.0231x over previous
//
#include <hip/hip_runtime.h>

// Problem constants (from setup_inputs): H=1536, W=2048, k=3, stride=4.
// k=3 is structural (window fully unrolled); stride read from d_in[2].
constexpr int H  = 1536;
constexpr int W  = 2048;
constexpr int PX = 8;                 // pixels per thread
// block = 256 threads = one full image row (256*8 = 2048); grid = H rows.
// Row swizzle: block i -> XCD i%8 (round-robin dispatch), so give each XCD a
// contiguous 192-row band: r = (i%8)*192 + i/8. Vertical 3x re-reads then hit
// that XCD's own L2 (1.6 MB band vs 4 MB L2) instead of re-fetching from HBM.

typedef float f32x4 __attribute__((ext_vector_type(4)));

__global__ __launch_bounds__(256)
void counting_post_kernel(const float* __restrict__ in,
                          const int* __restrict__ stride_p,
                          float* __restrict__ out) {
    const int bid = blockIdx.x;
    const int r   = (bid & 7) * (H / 8) + (bid >> 3);
    const int c0  = threadIdx.x * PX;
    const float s = (float)(*stride_p);

    // 3 rows x (PX+2) cols, relu'd, zero-padded at image borders.
    float v[3][PX + 2];
#pragma unroll
    for (int dr = 0; dr < 3; ++dr) {
        const int rr = r + dr - 1;
        if (rr < 0 || rr >= H) {
#pragma unroll
            for (int j = 0; j < PX + 2; ++j) v[dr][j] = 0.f;
        } else {
            const float* row = in + (size_t)rr * W + c0;
            const f32x4 a = *reinterpret_cast<const f32x4*>(row);
            const f32x4 b = *reinterpret_cast<const f32x4*>(row + 4);
            v[dr][1] = fmaxf(a.x, 0.f); v[dr][2] = fmaxf(a.y, 0.f);
            v[dr][3] = fmaxf(a.z, 0.f); v[dr][4] = fmaxf(a.w, 0.f);
            v[dr][5] = fmaxf(b.x, 0.f); v[dr][6] = fmaxf(b.y, 0.f);
            v[dr][7] = fmaxf(b.z, 0.f); v[dr][8] = fmaxf(b.w, 0.f);
            v[dr][0]      = (c0 > 0)      ? fmaxf(row[-1], 0.f) : 0.f;
            v[dr][PX + 1] = (c0 + PX < W) ? fmaxf(row[PX], 0.f) : 0.f;
        }
    }

    // Column sums and bottom-minus-top differences (shared across the 8 px).
    float cs[PX + 2], dv[PX + 2];
#pragma unroll
    for (int j = 0; j < PX + 2; ++j) {
        cs[j] = v[0][j] + v[1][j] + v[2][j];
        dv[j] = v[2][j] - v[0][j];
    }

    float f_o[PX], cw_o[PX], ch_o[PX];
    const float rf = (float)r;
#pragma unroll
    for (int p = 0; p < PX; ++p) {
        const float sum = cs[p] + cs[p + 1] + cs[p + 2];
        // wh = (r-1)*rs0 + r*rs1 + (r+1)*rs2 = r*sum + (rs2 - rs0)
        const float dh  = dv[p] + dv[p + 1] + dv[p + 2];
        // ww = (c-1)*cs0 + c*cs1 + (c+1)*cs2 = c*sum + (cs2 - cs0)
        const float dw  = cs[p + 2] - cs[p];

        // argmax-first-occurrence == center: strictly > earlier taps, >= later.
        const float w11 = v[1][p + 1];
        const bool mask = (w11 >  v[0][p]) && (w11 >  v[0][p+1]) && (w11 >  v[0][p+2])
                       && (w11 >  v[1][p])
                       && (w11 >= v[1][p+2])
                       && (w11 >= v[2][p]) && (w11 >= v[2][p+1]) && (w11 >= v[2][p+2]);
        f_o[p] = (sum > 0.5f && mask) ? 1.f : 0.f;

        const float inv = 1.f / fmaxf(sum, 1e-12f);
        const float cf  = (float)(c0 + p);
        const float wh  = fmaf(rf, sum, dh);
        const float ww  = fmaf(cf, sum, dw);
        cw_o[p] = fmaf(s, ww * inv, 0.5f);
        ch_o[p] = fmaf(s, wh * inv, 0.5f);
    }

    const size_t base  = (size_t)r * W + c0;
    const size_t plane = (size_t)H * W;
    f32x4* o0 = reinterpret_cast<f32x4*>(out + base);
    f32x4* o1 = reinterpret_cast<f32x4*>(out + plane + base);
    f32x4* o2 = reinterpret_cast<f32x4*>(out + 2 * plane + base);
    o0[0] = (f32x4){f_o[0],  f_o[1],  f_o[2],  f_o[3]};
    o0[1] = (f32x4){f_o[4],  f_o[5],  f_o[6],  f_o[7]};
    o1[0] = (f32x4){cw_o[0], cw_o[1], cw_o[2], cw_o[3]};
    o1[1] = (f32x4){cw_o[4], cw_o[5], cw_o[6], cw_o[7]};
    o2[0] = (f32x4){ch_o[0], ch_o[1], ch_o[2], ch_o[3]};
    o2[1] = (f32x4){ch_o[4], ch_o[5], ch_o[6], ch_o[7]};
}

extern "C" void kernel_launch(void* const* d_in, const int* in_sizes, int n_in,
                              void* d_out, int out_size, void* d_ws, size_t ws_size,
                              hipStream_t stream) {
    const float* in     = (const float*)d_in[0];
    const int*   stride = (const int*)d_in[2];   // d_in[1] = loc_kernel_size (=3, structural)
    float*       out    = (float*)d_out;

    counting_post_kernel<<<H, 256, 0, stream>>>(in, stride, out);
}